// Round 1
// baseline (3680.043 us; speedup 1.0000x reference)
//
#include <hip/hip_runtime.h>

#define N_NODES 50000
#define N_EDGES 800000
static constexpr float EPS = 1e-5f;

// ---------------------------------------------------------------------------
// prep: int32 src/dst extraction + in-degree count
// ---------------------------------------------------------------------------
__global__ __launch_bounds__(256) void k_prep(const int* __restrict__ ei,
                                              int* __restrict__ src,
                                              int* __restrict__ dst,
                                              int* __restrict__ deg) {
    int e = blockIdx.x * 256 + threadIdx.x;
    if (e >= N_EDGES) return;
    int s = ei[e];
    int d = ei[N_EDGES + e];
    src[e] = s;
    dst[e] = d;
    atomicAdd(&deg[d], 1);
}

__global__ __launch_bounds__(256) void k_inv(const int* __restrict__ deg,
                                             float* __restrict__ inv_sqrt,
                                             float* __restrict__ inv_deg) {
    int i = blockIdx.x * 256 + threadIdx.x;
    if (i >= N_NODES) return;
    float dg = (float)deg[i] + 1.0f;
    float r = rsqrtf(dg);
    inv_sqrt[i] = r;
    inv_deg[i] = r * r;   // matches ref: inv_sqrt*inv_sqrt
}

__global__ __launch_bounds__(256) void k_coef(const int* __restrict__ src,
                                              const int* __restrict__ dst,
                                              const float* __restrict__ inv_sqrt,
                                              float* __restrict__ coef) {
    int e = blockIdx.x * 256 + threadIdx.x;
    if (e >= N_EDGES) return;
    coef[e] = inv_sqrt[src[e]] * inv_sqrt[dst[e]];
}

// ---------------------------------------------------------------------------
// GEMM: H = act(A) @ W ; AGG = H * inv_deg + bias  (self-loop + bias fused)
// act = BN(scale/shift from stats)+ReLU when BN==true, identity otherwise.
// A is [N_NODES,128]; W is [128,NCOL]; 64 rows per block, 256 threads.
// ---------------------------------------------------------------------------
template <int NCOL, bool BN>
__global__ __launch_bounds__(256) void k_gemm(
    const float* __restrict__ A, const float* __restrict__ W,
    const float* __restrict__ bias, const float* __restrict__ stats,
    const float* __restrict__ gamma, const float* __restrict__ beta,
    const float* __restrict__ inv_deg,
    float* __restrict__ H, float* __restrict__ AGG) {
    constexpr int COLG = NCOL / 8;      // col groups of 8
    constexpr int RPT  = NCOL / 32;     // rows per thread (4 or 2)
    const int t = threadIdx.x;
    const int row0 = blockIdx.x * 64;

    __shared__ float As[64][132];       // +4 pad: 2-way LDS aliasing only (free)
    __shared__ float sc_s[128], sh_s[128];

    if (BN) {
        if (t < 128) {
            float s  = stats[t];
            float sq = stats[128 + t];
            float mean = s * (1.0f / N_NODES);
            float var  = sq * (1.0f / N_NODES) - mean * mean;
            float sc = gamma[t] * rsqrtf(var + EPS);
            sc_s[t] = sc;
            sh_s[t] = beta[t] - mean * sc;
        }
        __syncthreads();
    }

    // ---- stage A tile (with fused BN+ReLU) ----
    const int c4 = t & 31;   // float4 column index (cols c4*4..c4*4+3)
    const int rr = t >> 5;   // 0..7
#pragma unroll
    for (int i = 0; i < 8; i++) {
        int row = i * 8 + rr;
        float4 v = make_float4(0.f, 0.f, 0.f, 0.f);
        if (row0 + row < N_NODES)
            v = *(const float4*)&A[(size_t)(row0 + row) * 128 + c4 * 4];
        if (BN) {
            int c = c4 * 4;
            v.x = fmaxf(fmaf(v.x, sc_s[c + 0], sh_s[c + 0]), 0.f);
            v.y = fmaxf(fmaf(v.y, sc_s[c + 1], sh_s[c + 1]), 0.f);
            v.z = fmaxf(fmaf(v.z, sc_s[c + 2], sh_s[c + 2]), 0.f);
            v.w = fmaxf(fmaf(v.w, sc_s[c + 3], sh_s[c + 3]), 0.f);
        }
        *(float4*)&As[row][c4 * 4] = v;
    }
    __syncthreads();

    // ---- compute ----
    const int tx = t % COLG;            // col group
    const int ty = t / COLG;            // row group
    float acc[RPT][8];
#pragma unroll
    for (int r = 0; r < RPT; r++)
#pragma unroll
        for (int c = 0; c < 8; c++) acc[r][c] = 0.f;

    const float* Wp = W + tx * 8;
#pragma unroll 4
    for (int k = 0; k < 128; k++) {
        float a[RPT];
#pragma unroll
        for (int r = 0; r < RPT; r++) a[r] = As[ty * RPT + r][k];
        float4 w0 = *(const float4*)&Wp[k * NCOL];
        float4 w1 = *(const float4*)&Wp[k * NCOL + 4];
        float wv[8] = {w0.x, w0.y, w0.z, w0.w, w1.x, w1.y, w1.z, w1.w};
#pragma unroll
        for (int r = 0; r < RPT; r++)
#pragma unroll
            for (int c = 0; c < 8; c++)
                acc[r][c] = fmaf(a[r], wv[c], acc[r][c]);
    }

    // ---- epilogue: write H and AGG = H*inv_deg + bias ----
    float b8[8];
#pragma unroll
    for (int c = 0; c < 8; c++) b8[c] = bias[tx * 8 + c];
#pragma unroll
    for (int r = 0; r < RPT; r++) {
        int row = row0 + ty * RPT + r;
        if (row < N_NODES) {
            float idv = inv_deg[row];
            size_t base = (size_t)row * NCOL + tx * 8;
            float4 h0 = make_float4(acc[r][0], acc[r][1], acc[r][2], acc[r][3]);
            float4 h1 = make_float4(acc[r][4], acc[r][5], acc[r][6], acc[r][7]);
            *(float4*)&H[base]     = h0;
            *(float4*)&H[base + 4] = h1;
            float4 a0 = make_float4(fmaf(acc[r][0], idv, b8[0]), fmaf(acc[r][1], idv, b8[1]),
                                    fmaf(acc[r][2], idv, b8[2]), fmaf(acc[r][3], idv, b8[3]));
            float4 a1 = make_float4(fmaf(acc[r][4], idv, b8[4]), fmaf(acc[r][5], idv, b8[5]),
                                    fmaf(acc[r][6], idv, b8[6]), fmaf(acc[r][7], idv, b8[7]));
            *(float4*)&AGG[base]     = a0;
            *(float4*)&AGG[base + 4] = a1;
        }
    }
}

// ---------------------------------------------------------------------------
// edge aggregation: OUT[dst] += H[src] * coef   (fire-and-forget f32 atomics)
// one float4 of features per thread -> F/4 threads per edge
// ---------------------------------------------------------------------------
template <int F>
__global__ __launch_bounds__(256) void k_edge(const int* __restrict__ src,
                                              const int* __restrict__ dst,
                                              const float* __restrict__ coef,
                                              const float* __restrict__ H,
                                              float* __restrict__ OUT) {
    constexpr int TPE = F / 4;
    long long tid = (long long)blockIdx.x * 256 + threadIdx.x;
    int e  = (int)(tid / TPE);
    if (e >= N_EDGES) return;
    int fq = (int)(tid % TPE);
    int s = src[e];
    int d = dst[e];
    float c = coef[e];
    float4 h4 = *(const float4*)&H[(size_t)s * F + fq * 4];
    float* o = &OUT[(size_t)d * F + fq * 4];
    atomicAdd(o + 0, h4.x * c);
    atomicAdd(o + 1, h4.y * c);
    atomicAdd(o + 2, h4.z * c);
    atomicAdd(o + 3, h4.w * c);
}

// ---------------------------------------------------------------------------
// column stats: stats[0:128]=sum, stats[128:256]=sumsq over rows of A[N,128]
// ---------------------------------------------------------------------------
__global__ __launch_bounds__(256) void k_stats(const float* __restrict__ A,
                                               float* __restrict__ stats) {
    const int t  = threadIdx.x;
    const int c4 = t & 31;   // float4 col group
    const int rr = t >> 5;   // 0..7
    float4 sum = make_float4(0.f, 0.f, 0.f, 0.f);
    float4 sq  = make_float4(0.f, 0.f, 0.f, 0.f);
    for (int row = blockIdx.x * 8 + rr; row < N_NODES; row += gridDim.x * 8) {
        float4 v = *(const float4*)&A[(size_t)row * 128 + c4 * 4];
        sum.x += v.x; sum.y += v.y; sum.z += v.z; sum.w += v.w;
        sq.x += v.x * v.x; sq.y += v.y * v.y; sq.z += v.z * v.z; sq.w += v.w * v.w;
    }
    __shared__ float4 red[2][8][32];
    red[0][rr][c4] = sum;
    red[1][rr][c4] = sq;
    __syncthreads();
    if (t < 32) {
        float4 s = make_float4(0.f, 0.f, 0.f, 0.f);
        float4 q = make_float4(0.f, 0.f, 0.f, 0.f);
#pragma unroll
        for (int i = 0; i < 8; i++) {
            float4 a = red[0][i][t];
            float4 b = red[1][i][t];
            s.x += a.x; s.y += a.y; s.z += a.z; s.w += a.w;
            q.x += b.x; q.y += b.y; q.z += b.z; q.w += b.w;
        }
        int c = t * 4;
        atomicAdd(&stats[c + 0], s.x); atomicAdd(&stats[c + 1], s.y);
        atomicAdd(&stats[c + 2], s.z); atomicAdd(&stats[c + 3], s.w);
        atomicAdd(&stats[128 + c + 0], q.x); atomicAdd(&stats[128 + c + 1], q.y);
        atomicAdd(&stats[128 + c + 2], q.z); atomicAdd(&stats[128 + c + 3], q.w);
    }
}

// ---------------------------------------------------------------------------
extern "C" void kernel_launch(void* const* d_in, const int* in_sizes, int n_in,
                              void* d_out, int out_size, void* d_ws, size_t ws_size,
                              hipStream_t stream) {
    const float* x   = (const float*)d_in[0];
    const int*   ei  = (const int*)d_in[1];     // [2, E] int32
    const float* W1  = (const float*)d_in[2];
    const float* b1  = (const float*)d_in[3];
    const float* g1  = (const float*)d_in[4];
    const float* bt1 = (const float*)d_in[5];
    const float* W2  = (const float*)d_in[6];
    const float* b2  = (const float*)d_in[7];
    const float* g2  = (const float*)d_in[8];
    const float* bt2 = (const float*)d_in[9];
    const float* W3  = (const float*)d_in[10];
    const float* b3  = (const float*)d_in[11];
    float* out = (float*)d_out;                 // [N, 64]

    char* ws = (char*)d_ws;
    size_t off = 0;
    auto alloc = [&](size_t bytes) { char* p = ws + off; off += (bytes + 255) & ~(size_t)255; return p; };
    int*   deg      = (int*)  alloc((size_t)N_NODES * 4);
    float* inv_sqrt = (float*)alloc((size_t)N_NODES * 4);
    float* inv_deg  = (float*)alloc((size_t)N_NODES * 4);
    int*   src32    = (int*)  alloc((size_t)N_EDGES * 4);
    int*   dst32    = (int*)  alloc((size_t)N_EDGES * 4);
    float* coef     = (float*)alloc((size_t)N_EDGES * 4);
    float* stats1   = (float*)alloc(256 * 4);
    float* stats2   = (float*)alloc(256 * 4);
    float* h1       = (float*)alloc((size_t)N_NODES * 128 * 4);
    float* agg1     = (float*)alloc((size_t)N_NODES * 128 * 4);
    float* h2       = (float*)alloc((size_t)N_NODES * 128 * 4);
    float* agg2     = (float*)alloc((size_t)N_NODES * 128 * 4);
    float* h3       = (float*)alloc((size_t)N_NODES * 64 * 4);

    hipMemsetAsync(deg, 0, (size_t)N_NODES * 4, stream);
    hipMemsetAsync(stats1, 0, 256 * 4, stream);
    hipMemsetAsync(stats2, 0, 256 * 4, stream);

    k_prep<<<(N_EDGES + 255) / 256, 256, 0, stream>>>(ei, src32, dst32, deg);
    k_inv<<<(N_NODES + 255) / 256, 256, 0, stream>>>(deg, inv_sqrt, inv_deg);
    k_coef<<<(N_EDGES + 255) / 256, 256, 0, stream>>>(src32, dst32, inv_sqrt, coef);

    const int gemm_grid = (N_NODES + 63) / 64;

    // layer 1
    k_gemm<128, false><<<gemm_grid, 256, 0, stream>>>(x, W1, b1, nullptr, nullptr, nullptr,
                                                      inv_deg, h1, agg1);
    k_edge<128><<<(N_EDGES * 32 + 255) / 256, 256, 0, stream>>>(src32, dst32, coef, h1, agg1);
    k_stats<<<256, 256, 0, stream>>>(agg1, stats1);

    // layer 2
    k_gemm<128, true><<<gemm_grid, 256, 0, stream>>>(agg1, W2, b2, stats1, g1, bt1,
                                                     inv_deg, h2, agg2);
    k_edge<128><<<(N_EDGES * 32 + 255) / 256, 256, 0, stream>>>(src32, dst32, coef, h2, agg2);
    k_stats<<<256, 256, 0, stream>>>(agg2, stats2);

    // layer 3 (AGG -> d_out directly)
    k_gemm<64, true><<<gemm_grid, 256, 0, stream>>>(agg2, W3, b3, stats2, g2, bt2,
                                                    inv_deg, h3, out);
    k_edge<64><<<(N_EDGES * 16 + 255) / 256, 256, 0, stream>>>(src32, dst32, coef, h3, out);
}

// Round 2
// 622.714 us; speedup vs baseline: 5.9097x; 5.9097x over previous
//
#include <hip/hip_runtime.h>

#define N_NODES 50000
#define N_EDGES 800000
static constexpr float EPS = 1e-5f;

// ---------------------------------------------------------------------------
// prep: int32 src/dst extraction + in-degree histogram
// ---------------------------------------------------------------------------
__global__ __launch_bounds__(256) void k_prep(const int* __restrict__ ei,
                                              int* __restrict__ src,
                                              int* __restrict__ dst,
                                              int* __restrict__ deg) {
    int e = blockIdx.x * 256 + threadIdx.x;
    if (e >= N_EDGES) return;
    int s = ei[e];
    int d = ei[N_EDGES + e];
    src[e] = s;
    dst[e] = d;
    atomicAdd(&deg[d], 1);
}

__global__ __launch_bounds__(256) void k_inv(const int* __restrict__ deg,
                                             float* __restrict__ inv_sqrt,
                                             float* __restrict__ inv_deg) {
    int i = blockIdx.x * 256 + threadIdx.x;
    if (i >= N_NODES) return;
    float dg = (float)deg[i] + 1.0f;
    float r = rsqrtf(dg);
    inv_sqrt[i] = r;
    inv_deg[i] = r * r;   // matches ref: inv_sqrt*inv_sqrt
}

// ---------------------------------------------------------------------------
// single-block exclusive scan of deg[N] -> rowptr[N+1], cursor copy
// ---------------------------------------------------------------------------
__global__ __launch_bounds__(1024) void k_scan(const int* __restrict__ deg,
                                               int* __restrict__ rowptr,
                                               int* __restrict__ cursor) {
    const int t = threadIdx.x;
    constexpr int CH = (N_NODES + 1023) / 1024;   // 49
    const int beg = t * CH;
    const int end = min(beg + CH, N_NODES);
    int s = 0;
    for (int i = beg; i < end; i++) s += deg[i];
    __shared__ int part[1024];
    part[t] = s;
    __syncthreads();
    for (int off = 1; off < 1024; off <<= 1) {
        int v = (t >= off) ? part[t - off] : 0;
        __syncthreads();
        part[t] += v;
        __syncthreads();
    }
    int run = part[t] - s;   // exclusive prefix of this thread's chunk
    for (int i = beg; i < end; i++) {
        rowptr[i] = run;
        cursor[i] = run;
        run += deg[i];
    }
    if (t == 1023) rowptr[N_NODES] = N_EDGES;
}

// ---------------------------------------------------------------------------
// fill CSR buckets: esrc[pos]=src, ecoef[pos]=inv_sqrt[s]*inv_sqrt[d]
// ---------------------------------------------------------------------------
__global__ __launch_bounds__(256) void k_fill(const int* __restrict__ src,
                                              const int* __restrict__ dst,
                                              const float* __restrict__ inv_sqrt,
                                              int* __restrict__ cursor,
                                              int* __restrict__ esrc,
                                              float* __restrict__ ecoef) {
    int e = blockIdx.x * 256 + threadIdx.x;
    if (e >= N_EDGES) return;
    int s = src[e];
    int d = dst[e];
    int pos = atomicAdd(&cursor[d], 1);
    esrc[pos] = s;
    ecoef[pos] = inv_sqrt[s] * inv_sqrt[d];
}

// ---------------------------------------------------------------------------
// GEMM: H = act(A) @ W  (act = BN+ReLU when BN, identity otherwise)
// A is [N_NODES,128]; W is [128,NCOL]; 64 rows per block, 256 threads.
// ---------------------------------------------------------------------------
template <int NCOL, bool BN>
__global__ __launch_bounds__(256) void k_gemm(
    const float* __restrict__ A, const float* __restrict__ W,
    const float* __restrict__ stats,
    const float* __restrict__ gamma, const float* __restrict__ beta,
    float* __restrict__ H) {
    constexpr int COLG = NCOL / 8;      // col groups of 8
    constexpr int RPT  = NCOL / 32;     // rows per thread (4 or 2)
    const int t = threadIdx.x;
    const int row0 = blockIdx.x * 64;

    __shared__ float As[64][132];       // +4 pad: 2-way LDS aliasing only (free)
    __shared__ float sc_s[128], sh_s[128];

    if (BN) {
        if (t < 128) {
            float s  = stats[t];
            float sq = stats[128 + t];
            float mean = s * (1.0f / N_NODES);
            float var  = sq * (1.0f / N_NODES) - mean * mean;
            float sc = gamma[t] * rsqrtf(var + EPS);
            sc_s[t] = sc;
            sh_s[t] = beta[t] - mean * sc;
        }
        __syncthreads();
    }

    // ---- stage A tile (with fused BN+ReLU) ----
    const int c4 = t & 31;   // float4 column index
    const int rr = t >> 5;   // 0..7
#pragma unroll
    for (int i = 0; i < 8; i++) {
        int row = i * 8 + rr;
        float4 v = make_float4(0.f, 0.f, 0.f, 0.f);
        if (row0 + row < N_NODES)
            v = *(const float4*)&A[(size_t)(row0 + row) * 128 + c4 * 4];
        if (BN) {
            int c = c4 * 4;
            v.x = fmaxf(fmaf(v.x, sc_s[c + 0], sh_s[c + 0]), 0.f);
            v.y = fmaxf(fmaf(v.y, sc_s[c + 1], sh_s[c + 1]), 0.f);
            v.z = fmaxf(fmaf(v.z, sc_s[c + 2], sh_s[c + 2]), 0.f);
            v.w = fmaxf(fmaf(v.w, sc_s[c + 3], sh_s[c + 3]), 0.f);
        }
        *(float4*)&As[row][c4 * 4] = v;
    }
    __syncthreads();

    // ---- compute ----
    const int tx = t % COLG;
    const int ty = t / COLG;
    float acc[RPT][8];
#pragma unroll
    for (int r = 0; r < RPT; r++)
#pragma unroll
        for (int c = 0; c < 8; c++) acc[r][c] = 0.f;

    const float* Wp = W + tx * 8;
#pragma unroll 4
    for (int k = 0; k < 128; k++) {
        float a[RPT];
#pragma unroll
        for (int r = 0; r < RPT; r++) a[r] = As[ty * RPT + r][k];
        float4 w0 = *(const float4*)&Wp[k * NCOL];
        float4 w1 = *(const float4*)&Wp[k * NCOL + 4];
        float wv[8] = {w0.x, w0.y, w0.z, w0.w, w1.x, w1.y, w1.z, w1.w};
#pragma unroll
        for (int r = 0; r < RPT; r++)
#pragma unroll
            for (int c = 0; c < 8; c++)
                acc[r][c] = fmaf(a[r], wv[c], acc[r][c]);
    }

    // ---- epilogue: write H ----
#pragma unroll
    for (int r = 0; r < RPT; r++) {
        int row = row0 + ty * RPT + r;
        if (row < N_NODES) {
            size_t base = (size_t)row * NCOL + tx * 8;
            *(float4*)&H[base]     = make_float4(acc[r][0], acc[r][1], acc[r][2], acc[r][3]);
            *(float4*)&H[base + 4] = make_float4(acc[r][4], acc[r][5], acc[r][6], acc[r][7]);
        }
    }
}

// ---------------------------------------------------------------------------
// CSR gather-aggregate: OUT[n] = sum_{e in bucket(n)} H[esrc[e]]*ecoef[e]
//                              + H[n]*inv_deg[n] + bias
// F/4 lanes per node, float4 per lane; one write per output element.
// ---------------------------------------------------------------------------
template <int F>
__global__ __launch_bounds__(256) void k_agg(const int* __restrict__ rowptr,
                                             const int* __restrict__ esrc,
                                             const float* __restrict__ ecoef,
                                             const float* __restrict__ H,
                                             const float* __restrict__ inv_deg,
                                             const float* __restrict__ bias,
                                             float* __restrict__ OUT) {
    constexpr int LPN = F / 4;              // lanes per node (32 or 16)
    constexpr int NPB = 256 / LPN;          // nodes per block (8 or 16)
    const int t = threadIdx.x;
    const int node = blockIdx.x * NPB + t / LPN;
    const int lane = t % LPN;
    if (node >= N_NODES) return;

    const float4* __restrict__ Hv = (const float4*)H;
    const int beg = rowptr[node];
    const int end = rowptr[node + 1];

    float4 acc = make_float4(0.f, 0.f, 0.f, 0.f);
    int j = beg;
    for (; j + 1 < end; j += 2) {
        int s0 = esrc[j], s1 = esrc[j + 1];
        float c0 = ecoef[j], c1 = ecoef[j + 1];
        float4 h0 = Hv[(size_t)s0 * LPN + lane];
        float4 h1 = Hv[(size_t)s1 * LPN + lane];
        acc.x = fmaf(h0.x, c0, acc.x); acc.y = fmaf(h0.y, c0, acc.y);
        acc.z = fmaf(h0.z, c0, acc.z); acc.w = fmaf(h0.w, c0, acc.w);
        acc.x = fmaf(h1.x, c1, acc.x); acc.y = fmaf(h1.y, c1, acc.y);
        acc.z = fmaf(h1.z, c1, acc.z); acc.w = fmaf(h1.w, c1, acc.w);
    }
    if (j < end) {
        int s0 = esrc[j];
        float c0 = ecoef[j];
        float4 h0 = Hv[(size_t)s0 * LPN + lane];
        acc.x = fmaf(h0.x, c0, acc.x); acc.y = fmaf(h0.y, c0, acc.y);
        acc.z = fmaf(h0.z, c0, acc.z); acc.w = fmaf(h0.w, c0, acc.w);
    }

    // self-loop + bias
    float4 hs = Hv[(size_t)node * LPN + lane];
    float idv = inv_deg[node];
    float4 b4 = ((const float4*)bias)[lane];
    acc.x = fmaf(hs.x, idv, acc.x) + b4.x;
    acc.y = fmaf(hs.y, idv, acc.y) + b4.y;
    acc.z = fmaf(hs.z, idv, acc.z) + b4.z;
    acc.w = fmaf(hs.w, idv, acc.w) + b4.w;

    ((float4*)OUT)[(size_t)node * LPN + lane] = acc;
}

// ---------------------------------------------------------------------------
// column stats: stats[0:128]=sum, stats[128:256]=sumsq over rows of A[N,128]
// ---------------------------------------------------------------------------
__global__ __launch_bounds__(256) void k_stats(const float* __restrict__ A,
                                               float* __restrict__ stats) {
    const int t  = threadIdx.x;
    const int c4 = t & 31;
    const int rr = t >> 5;
    float4 sum = make_float4(0.f, 0.f, 0.f, 0.f);
    float4 sq  = make_float4(0.f, 0.f, 0.f, 0.f);
    for (int row = blockIdx.x * 8 + rr; row < N_NODES; row += gridDim.x * 8) {
        float4 v = *(const float4*)&A[(size_t)row * 128 + c4 * 4];
        sum.x += v.x; sum.y += v.y; sum.z += v.z; sum.w += v.w;
        sq.x += v.x * v.x; sq.y += v.y * v.y; sq.z += v.z * v.z; sq.w += v.w * v.w;
    }
    __shared__ float4 red[2][8][32];
    red[0][rr][c4] = sum;
    red[1][rr][c4] = sq;
    __syncthreads();
    if (t < 32) {
        float4 s = make_float4(0.f, 0.f, 0.f, 0.f);
        float4 q = make_float4(0.f, 0.f, 0.f, 0.f);
#pragma unroll
        for (int i = 0; i < 8; i++) {
            float4 a = red[0][i][t];
            float4 b = red[1][i][t];
            s.x += a.x; s.y += a.y; s.z += a.z; s.w += a.w;
            q.x += b.x; q.y += b.y; q.z += b.z; q.w += b.w;
        }
        int c = t * 4;
        atomicAdd(&stats[c + 0], s.x); atomicAdd(&stats[c + 1], s.y);
        atomicAdd(&stats[c + 2], s.z); atomicAdd(&stats[c + 3], s.w);
        atomicAdd(&stats[128 + c + 0], q.x); atomicAdd(&stats[128 + c + 1], q.y);
        atomicAdd(&stats[128 + c + 2], q.z); atomicAdd(&stats[128 + c + 3], q.w);
    }
}

// ---------------------------------------------------------------------------
extern "C" void kernel_launch(void* const* d_in, const int* in_sizes, int n_in,
                              void* d_out, int out_size, void* d_ws, size_t ws_size,
                              hipStream_t stream) {
    const float* x   = (const float*)d_in[0];
    const int*   ei  = (const int*)d_in[1];     // [2, E] int32
    const float* W1  = (const float*)d_in[2];
    const float* b1  = (const float*)d_in[3];
    const float* g1  = (const float*)d_in[4];
    const float* bt1 = (const float*)d_in[5];
    const float* W2  = (const float*)d_in[6];
    const float* b2  = (const float*)d_in[7];
    const float* g2  = (const float*)d_in[8];
    const float* bt2 = (const float*)d_in[9];
    const float* W3  = (const float*)d_in[10];
    const float* b3  = (const float*)d_in[11];
    float* out = (float*)d_out;                 // [N, 64]

    char* ws = (char*)d_ws;
    size_t off = 0;
    auto alloc = [&](size_t bytes) { char* p = ws + off; off += (bytes + 255) & ~(size_t)255; return p; };
    int*   deg      = (int*)  alloc((size_t)N_NODES * 4);
    float* inv_sqrt = (float*)alloc((size_t)N_NODES * 4);
    float* inv_deg  = (float*)alloc((size_t)N_NODES * 4);
    int*   rowptr   = (int*)  alloc((size_t)(N_NODES + 1) * 4);
    int*   cursor   = (int*)  alloc((size_t)N_NODES * 4);
    int*   src32    = (int*)  alloc((size_t)N_EDGES * 4);
    int*   dst32    = (int*)  alloc((size_t)N_EDGES * 4);
    int*   esrc     = (int*)  alloc((size_t)N_EDGES * 4);
    float* ecoef    = (float*)alloc((size_t)N_EDGES * 4);
    float* stats1   = (float*)alloc(256 * 4);
    float* stats2   = (float*)alloc(256 * 4);
    float* h1       = (float*)alloc((size_t)N_NODES * 128 * 4);
    float* agg1     = (float*)alloc((size_t)N_NODES * 128 * 4);
    float* h2       = (float*)alloc((size_t)N_NODES * 128 * 4);
    float* agg2     = (float*)alloc((size_t)N_NODES * 128 * 4);
    float* h3       = (float*)alloc((size_t)N_NODES * 64 * 4);

    hipMemsetAsync(deg, 0, (size_t)N_NODES * 4, stream);
    hipMemsetAsync(stats1, 0, 256 * 4, stream);
    hipMemsetAsync(stats2, 0, 256 * 4, stream);

    k_prep<<<(N_EDGES + 255) / 256, 256, 0, stream>>>(ei, src32, dst32, deg);
    k_inv<<<(N_NODES + 255) / 256, 256, 0, stream>>>(deg, inv_sqrt, inv_deg);
    k_scan<<<1, 1024, 0, stream>>>(deg, rowptr, cursor);
    k_fill<<<(N_EDGES + 255) / 256, 256, 0, stream>>>(src32, dst32, inv_sqrt, cursor, esrc, ecoef);

    const int gemm_grid = (N_NODES + 63) / 64;

    // layer 1
    k_gemm<128, false><<<gemm_grid, 256, 0, stream>>>(x, W1, nullptr, nullptr, nullptr, h1);
    k_agg<128><<<(N_NODES + 7) / 8, 256, 0, stream>>>(rowptr, esrc, ecoef, h1, inv_deg, b1, agg1);
    k_stats<<<256, 256, 0, stream>>>(agg1, stats1);

    // layer 2
    k_gemm<128, true><<<gemm_grid, 256, 0, stream>>>(agg1, W2, stats1, g1, bt1, h2);
    k_agg<128><<<(N_NODES + 7) / 8, 256, 0, stream>>>(rowptr, esrc, ecoef, h2, inv_deg, b2, agg2);
    k_stats<<<256, 256, 0, stream>>>(agg2, stats2);

    // layer 3 (aggregate straight into d_out)
    k_gemm<64, true><<<gemm_grid, 256, 0, stream>>>(agg2, W3, stats2, g2, bt2, h3);
    k_agg<64><<<(N_NODES + 15) / 16, 256, 0, stream>>>(rowptr, esrc, ecoef, h3, inv_deg, b3, out);
}

// Round 3
// 506.295 us; speedup vs baseline: 7.2686x; 1.2299x over previous
//
#include <hip/hip_runtime.h>

#define N_NODES 50000
#define N_EDGES 800000
static constexpr float EPS = 1e-5f;
static constexpr int SCAN_NB = (N_NODES + 255) / 256;   // 196

// ---------------------------------------------------------------------------
// prep: in-degree histogram (reads dst half of edge_index directly)
// ---------------------------------------------------------------------------
__global__ __launch_bounds__(256) void k_prep(const int* __restrict__ ei,
                                              int* __restrict__ deg) {
    int e = blockIdx.x * 256 + threadIdx.x;
    if (e >= N_EDGES) return;
    atomicAdd(&deg[ei[N_EDGES + e]], 1);
}

__global__ __launch_bounds__(256) void k_inv(const int* __restrict__ deg,
                                             float* __restrict__ inv_sqrt,
                                             float* __restrict__ inv_deg) {
    int i = blockIdx.x * 256 + threadIdx.x;
    if (i >= N_NODES) return;
    float dg = (float)deg[i] + 1.0f;
    float r = rsqrtf(dg);
    inv_sqrt[i] = r;
    inv_deg[i] = r * r;   // matches ref: inv_sqrt*inv_sqrt
}

// ---------------------------------------------------------------------------
// hierarchical exclusive scan: deg[N] -> rowptr[N+1] (+cursor copy)
// stage 1: block-local exclusive scan + block totals
// ---------------------------------------------------------------------------
__global__ __launch_bounds__(256) void k_scan1(const int* __restrict__ deg,
                                               int* __restrict__ excl,
                                               int* __restrict__ partials) {
    const int t = threadIdx.x;
    const int i = blockIdx.x * 256 + t;
    int v = (i < N_NODES) ? deg[i] : 0;
    __shared__ int sh[256];
    sh[t] = v;
    __syncthreads();
    for (int off = 1; off < 256; off <<= 1) {
        int u = (t >= off) ? sh[t - off] : 0;
        __syncthreads();
        sh[t] += u;
        __syncthreads();
    }
    if (i < N_NODES) excl[i] = sh[t] - v;          // block-local exclusive
    if (t == 255) partials[blockIdx.x] = sh[t];    // block total
}

// stage 2: single block scans the 196 block totals -> exclusive offsets
__global__ __launch_bounds__(256) void k_scan2(int* __restrict__ partials) {
    const int t = threadIdx.x;
    int v = (t < SCAN_NB) ? partials[t] : 0;
    __shared__ int sh[256];
    sh[t] = v;
    __syncthreads();
    for (int off = 1; off < 256; off <<= 1) {
        int u = (t >= off) ? sh[t - off] : 0;
        __syncthreads();
        sh[t] += u;
        __syncthreads();
    }
    if (t < SCAN_NB) partials[t] = sh[t] - v;      // exclusive block offset
}

// stage 3: apply block offsets -> rowptr, cursor
__global__ __launch_bounds__(256) void k_scan3(const int* __restrict__ excl,
                                               const int* __restrict__ partials,
                                               int* __restrict__ rowptr,
                                               int* __restrict__ cursor) {
    const int i = blockIdx.x * 256 + threadIdx.x;
    if (i < N_NODES) {
        int r = excl[i] + partials[blockIdx.x];
        rowptr[i] = r;
        cursor[i] = r;
    }
    if (i == 0) rowptr[N_NODES] = N_EDGES;
}

// ---------------------------------------------------------------------------
// fill CSR buckets: esrc[pos]=src, ecoef[pos]=inv_sqrt[s]*inv_sqrt[d]
// ---------------------------------------------------------------------------
__global__ __launch_bounds__(256) void k_fill(const int* __restrict__ ei,
                                              const float* __restrict__ inv_sqrt,
                                              int* __restrict__ cursor,
                                              int* __restrict__ esrc,
                                              float* __restrict__ ecoef) {
    int e = blockIdx.x * 256 + threadIdx.x;
    if (e >= N_EDGES) return;
    int s = ei[e];
    int d = ei[N_EDGES + e];
    int pos = atomicAdd(&cursor[d], 1);
    esrc[pos] = s;
    ecoef[pos] = inv_sqrt[s] * inv_sqrt[d];
}

// ---------------------------------------------------------------------------
// GEMM: H = act(A) @ W  (act = BN+ReLU when BN, identity otherwise)
// A is [N_NODES,128]; W is [128,NCOL]; 64 rows per block, 256 threads.
// ---------------------------------------------------------------------------
template <int NCOL, bool BN>
__global__ __launch_bounds__(256) void k_gemm(
    const float* __restrict__ A, const float* __restrict__ W,
    const float* __restrict__ stats,
    const float* __restrict__ gamma, const float* __restrict__ beta,
    float* __restrict__ H) {
    constexpr int COLG = NCOL / 8;      // col groups of 8
    constexpr int RPT  = NCOL / 32;     // rows per thread (4 or 2)
    const int t = threadIdx.x;
    const int row0 = blockIdx.x * 64;

    __shared__ float As[64][132];       // +4 pad: 2-way LDS aliasing only (free)
    __shared__ float sc_s[128], sh_s[128];

    if (BN) {
        if (t < 128) {
            float s  = stats[t];
            float sq = stats[128 + t];
            float mean = s * (1.0f / N_NODES);
            float var  = sq * (1.0f / N_NODES) - mean * mean;
            float sc = gamma[t] * rsqrtf(var + EPS);
            sc_s[t] = sc;
            sh_s[t] = beta[t] - mean * sc;
        }
        __syncthreads();
    }

    // ---- stage A tile (with fused BN+ReLU) ----
    const int c4 = t & 31;   // float4 column index
    const int rr = t >> 5;   // 0..7
#pragma unroll
    for (int i = 0; i < 8; i++) {
        int row = i * 8 + rr;
        float4 v = make_float4(0.f, 0.f, 0.f, 0.f);
        if (row0 + row < N_NODES)
            v = *(const float4*)&A[(size_t)(row0 + row) * 128 + c4 * 4];
        if (BN) {
            int c = c4 * 4;
            v.x = fmaxf(fmaf(v.x, sc_s[c + 0], sh_s[c + 0]), 0.f);
            v.y = fmaxf(fmaf(v.y, sc_s[c + 1], sh_s[c + 1]), 0.f);
            v.z = fmaxf(fmaf(v.z, sc_s[c + 2], sh_s[c + 2]), 0.f);
            v.w = fmaxf(fmaf(v.w, sc_s[c + 3], sh_s[c + 3]), 0.f);
        }
        *(float4*)&As[row][c4 * 4] = v;
    }
    __syncthreads();

    // ---- compute ----
    const int tx = t % COLG;
    const int ty = t / COLG;
    float acc[RPT][8];
#pragma unroll
    for (int r = 0; r < RPT; r++)
#pragma unroll
        for (int c = 0; c < 8; c++) acc[r][c] = 0.f;

    const float* Wp = W + tx * 8;
#pragma unroll 4
    for (int k = 0; k < 128; k++) {
        float a[RPT];
#pragma unroll
        for (int r = 0; r < RPT; r++) a[r] = As[ty * RPT + r][k];
        float4 w0 = *(const float4*)&Wp[k * NCOL];
        float4 w1 = *(const float4*)&Wp[k * NCOL + 4];
        float wv[8] = {w0.x, w0.y, w0.z, w0.w, w1.x, w1.y, w1.z, w1.w};
#pragma unroll
        for (int r = 0; r < RPT; r++)
#pragma unroll
            for (int c = 0; c < 8; c++)
                acc[r][c] = fmaf(a[r], wv[c], acc[r][c]);
    }

    // ---- epilogue: write H ----
#pragma unroll
    for (int r = 0; r < RPT; r++) {
        int row = row0 + ty * RPT + r;
        if (row < N_NODES) {
            size_t base = (size_t)row * NCOL + tx * 8;
            *(float4*)&H[base]     = make_float4(acc[r][0], acc[r][1], acc[r][2], acc[r][3]);
            *(float4*)&H[base + 4] = make_float4(acc[r][4], acc[r][5], acc[r][6], acc[r][7]);
        }
    }
}

// ---------------------------------------------------------------------------
// CSR gather-aggregate: OUT[n] = sum_{e in bucket(n)} H[esrc[e]]*ecoef[e]
//                              + H[n]*inv_deg[n] + bias
// F/4 lanes per node, float4 per lane; one write per output element.
// ---------------------------------------------------------------------------
template <int F>
__global__ __launch_bounds__(256) void k_agg(const int* __restrict__ rowptr,
                                             const int* __restrict__ esrc,
                                             const float* __restrict__ ecoef,
                                             const float* __restrict__ H,
                                             const float* __restrict__ inv_deg,
                                             const float* __restrict__ bias,
                                             float* __restrict__ OUT) {
    constexpr int LPN = F / 4;              // lanes per node (32 or 16)
    constexpr int NPB = 256 / LPN;          // nodes per block (8 or 16)
    const int t = threadIdx.x;
    const int node = blockIdx.x * NPB + t / LPN;
    const int lane = t % LPN;
    if (node >= N_NODES) return;

    const float4* __restrict__ Hv = (const float4*)H;
    const int beg = rowptr[node];
    const int end = rowptr[node + 1];

    float4 acc = make_float4(0.f, 0.f, 0.f, 0.f);
    int j = beg;
    for (; j + 1 < end; j += 2) {
        int s0 = esrc[j], s1 = esrc[j + 1];
        float c0 = ecoef[j], c1 = ecoef[j + 1];
        float4 h0 = Hv[(size_t)s0 * LPN + lane];
        float4 h1 = Hv[(size_t)s1 * LPN + lane];
        acc.x = fmaf(h0.x, c0, acc.x); acc.y = fmaf(h0.y, c0, acc.y);
        acc.z = fmaf(h0.z, c0, acc.z); acc.w = fmaf(h0.w, c0, acc.w);
        acc.x = fmaf(h1.x, c1, acc.x); acc.y = fmaf(h1.y, c1, acc.y);
        acc.z = fmaf(h1.z, c1, acc.z); acc.w = fmaf(h1.w, c1, acc.w);
    }
    if (j < end) {
        int s0 = esrc[j];
        float c0 = ecoef[j];
        float4 h0 = Hv[(size_t)s0 * LPN + lane];
        acc.x = fmaf(h0.x, c0, acc.x); acc.y = fmaf(h0.y, c0, acc.y);
        acc.z = fmaf(h0.z, c0, acc.z); acc.w = fmaf(h0.w, c0, acc.w);
    }

    // self-loop + bias
    float4 hs = Hv[(size_t)node * LPN + lane];
    float idv = inv_deg[node];
    float4 b4 = ((const float4*)bias)[lane];
    acc.x = fmaf(hs.x, idv, acc.x) + b4.x;
    acc.y = fmaf(hs.y, idv, acc.y) + b4.y;
    acc.z = fmaf(hs.z, idv, acc.z) + b4.z;
    acc.w = fmaf(hs.w, idv, acc.w) + b4.w;

    ((float4*)OUT)[(size_t)node * LPN + lane] = acc;
}

// ---------------------------------------------------------------------------
// column stats: stats[0:128]=sum, stats[128:256]=sumsq over rows of A[N,128]
// ---------------------------------------------------------------------------
__global__ __launch_bounds__(256) void k_stats(const float* __restrict__ A,
                                               float* __restrict__ stats) {
    const int t  = threadIdx.x;
    const int c4 = t & 31;
    const int rr = t >> 5;
    float4 sum = make_float4(0.f, 0.f, 0.f, 0.f);
    float4 sq  = make_float4(0.f, 0.f, 0.f, 0.f);
    for (int row = blockIdx.x * 8 + rr; row < N_NODES; row += gridDim.x * 8) {
        float4 v = *(const float4*)&A[(size_t)row * 128 + c4 * 4];
        sum.x += v.x; sum.y += v.y; sum.z += v.z; sum.w += v.w;
        sq.x += v.x * v.x; sq.y += v.y * v.y; sq.z += v.z * v.z; sq.w += v.w * v.w;
    }
    __shared__ float4 red[2][8][32];
    red[0][rr][c4] = sum;
    red[1][rr][c4] = sq;
    __syncthreads();
    if (t < 32) {
        float4 s = make_float4(0.f, 0.f, 0.f, 0.f);
        float4 q = make_float4(0.f, 0.f, 0.f, 0.f);
#pragma unroll
        for (int i = 0; i < 8; i++) {
            float4 a = red[0][i][t];
            float4 b = red[1][i][t];
            s.x += a.x; s.y += a.y; s.z += a.z; s.w += a.w;
            q.x += b.x; q.y += b.y; q.z += b.z; q.w += b.w;
        }
        int c = t * 4;
        atomicAdd(&stats[c + 0], s.x); atomicAdd(&stats[c + 1], s.y);
        atomicAdd(&stats[c + 2], s.z); atomicAdd(&stats[c + 3], s.w);
        atomicAdd(&stats[128 + c + 0], q.x); atomicAdd(&stats[128 + c + 1], q.y);
        atomicAdd(&stats[128 + c + 2], q.z); atomicAdd(&stats[128 + c + 3], q.w);
    }
}

// ---------------------------------------------------------------------------
extern "C" void kernel_launch(void* const* d_in, const int* in_sizes, int n_in,
                              void* d_out, int out_size, void* d_ws, size_t ws_size,
                              hipStream_t stream) {
    const float* x   = (const float*)d_in[0];
    const int*   ei  = (const int*)d_in[1];     // [2, E] int32
    const float* W1  = (const float*)d_in[2];
    const float* b1  = (const float*)d_in[3];
    const float* g1  = (const float*)d_in[4];
    const float* bt1 = (const float*)d_in[5];
    const float* W2  = (const float*)d_in[6];
    const float* b2  = (const float*)d_in[7];
    const float* g2  = (const float*)d_in[8];
    const float* bt2 = (const float*)d_in[9];
    const float* W3  = (const float*)d_in[10];
    const float* b3  = (const float*)d_in[11];
    float* out = (float*)d_out;                 // [N, 64]

    char* ws = (char*)d_ws;
    size_t off = 0;
    auto alloc = [&](size_t bytes) { char* p = ws + off; off += (bytes + 255) & ~(size_t)255; return p; };
    int*   deg      = (int*)  alloc((size_t)N_NODES * 4);
    float* inv_sqrt = (float*)alloc((size_t)N_NODES * 4);
    float* inv_deg  = (float*)alloc((size_t)N_NODES * 4);
    int*   excl     = (int*)  alloc((size_t)N_NODES * 4);
    int*   partials = (int*)  alloc(256 * 4);
    int*   rowptr   = (int*)  alloc((size_t)(N_NODES + 1) * 4);
    int*   cursor   = (int*)  alloc((size_t)N_NODES * 4);
    int*   esrc     = (int*)  alloc((size_t)N_EDGES * 4);
    float* ecoef    = (float*)alloc((size_t)N_EDGES * 4);
    float* stats1   = (float*)alloc(256 * 4);
    float* stats2   = (float*)alloc(256 * 4);
    float* h1       = (float*)alloc((size_t)N_NODES * 128 * 4);
    float* agg1     = (float*)alloc((size_t)N_NODES * 128 * 4);
    float* h2       = (float*)alloc((size_t)N_NODES * 128 * 4);
    float* agg2     = (float*)alloc((size_t)N_NODES * 128 * 4);
    float* h3       = (float*)alloc((size_t)N_NODES * 64 * 4);

    hipMemsetAsync(deg, 0, (size_t)N_NODES * 4, stream);
    hipMemsetAsync(stats1, 0, 256 * 4, stream);
    hipMemsetAsync(stats2, 0, 256 * 4, stream);

    k_prep<<<(N_EDGES + 255) / 256, 256, 0, stream>>>(ei, deg);
    k_inv<<<(N_NODES + 255) / 256, 256, 0, stream>>>(deg, inv_sqrt, inv_deg);
    k_scan1<<<SCAN_NB, 256, 0, stream>>>(deg, excl, partials);
    k_scan2<<<1, 256, 0, stream>>>(partials);
    k_scan3<<<SCAN_NB, 256, 0, stream>>>(excl, partials, rowptr, cursor);
    k_fill<<<(N_EDGES + 255) / 256, 256, 0, stream>>>(ei, inv_sqrt, cursor, esrc, ecoef);

    const int gemm_grid = (N_NODES + 63) / 64;

    // layer 1
    k_gemm<128, false><<<gemm_grid, 256, 0, stream>>>(x, W1, nullptr, nullptr, nullptr, h1);
    k_agg<128><<<(N_NODES + 7) / 8, 256, 0, stream>>>(rowptr, esrc, ecoef, h1, inv_deg, b1, agg1);
    k_stats<<<256, 256, 0, stream>>>(agg1, stats1);

    // layer 2
    k_gemm<128, true><<<gemm_grid, 256, 0, stream>>>(agg1, W2, stats1, g1, bt1, h2);
    k_agg<128><<<(N_NODES + 7) / 8, 256, 0, stream>>>(rowptr, esrc, ecoef, h2, inv_deg, b2, agg2);
    k_stats<<<256, 256, 0, stream>>>(agg2, stats2);

    // layer 3 (aggregate straight into d_out)
    k_gemm<64, true><<<gemm_grid, 256, 0, stream>>>(agg2, W3, stats2, g2, bt2, h3);
    k_agg<64><<<(N_NODES + 15) / 16, 256, 0, stream>>>(rowptr, esrc, ecoef, h3, inv_deg, b3, out);
}

// Round 4
// 469.064 us; speedup vs baseline: 7.8455x; 1.0794x over previous
//
#include <hip/hip_runtime.h>

#define N_NODES 50000
#define N_EDGES 800000
static constexpr float EPS = 1e-5f;
static constexpr int SCAN_NB = (N_NODES + 255) / 256;   // 196

// ---- bf16 helpers (raw-bit, RNE) ----
static __device__ __forceinline__ unsigned short f2bf(float f) {
    unsigned int u = __float_as_uint(f);
    return (unsigned short)((u + 0x7FFFu + ((u >> 16) & 1u)) >> 16);
}
static __device__ __forceinline__ float blo(unsigned int w) { return __uint_as_float(w << 16); }
static __device__ __forceinline__ float bhi(unsigned int w) { return __uint_as_float(w & 0xffff0000u); }

// ---------------------------------------------------------------------------
// prep: in-degree histogram (reads dst half of edge_index directly)
// ---------------------------------------------------------------------------
__global__ __launch_bounds__(256) void k_prep(const int* __restrict__ ei,
                                              int* __restrict__ deg) {
    int e = blockIdx.x * 256 + threadIdx.x;
    if (e >= N_EDGES) return;
    atomicAdd(&deg[ei[N_EDGES + e]], 1);
}

__global__ __launch_bounds__(256) void k_inv(const int* __restrict__ deg,
                                             float* __restrict__ inv_sqrt,
                                             float* __restrict__ inv_deg) {
    int i = blockIdx.x * 256 + threadIdx.x;
    if (i >= N_NODES) return;
    float dg = (float)deg[i] + 1.0f;
    float r = rsqrtf(dg);
    inv_sqrt[i] = r;
    inv_deg[i] = r * r;   // matches ref: inv_sqrt*inv_sqrt
}

// ---------------------------------------------------------------------------
// hierarchical exclusive scan: deg[N] -> rowptr[N+1] (+cursor copy)
// ---------------------------------------------------------------------------
__global__ __launch_bounds__(256) void k_scan1(const int* __restrict__ deg,
                                               int* __restrict__ excl,
                                               int* __restrict__ partials) {
    const int t = threadIdx.x;
    const int i = blockIdx.x * 256 + t;
    int v = (i < N_NODES) ? deg[i] : 0;
    __shared__ int sh[256];
    sh[t] = v;
    __syncthreads();
    for (int off = 1; off < 256; off <<= 1) {
        int u = (t >= off) ? sh[t - off] : 0;
        __syncthreads();
        sh[t] += u;
        __syncthreads();
    }
    if (i < N_NODES) excl[i] = sh[t] - v;
    if (t == 255) partials[blockIdx.x] = sh[t];
}

__global__ __launch_bounds__(256) void k_scan2(int* __restrict__ partials) {
    const int t = threadIdx.x;
    int v = (t < SCAN_NB) ? partials[t] : 0;
    __shared__ int sh[256];
    sh[t] = v;
    __syncthreads();
    for (int off = 1; off < 256; off <<= 1) {
        int u = (t >= off) ? sh[t - off] : 0;
        __syncthreads();
        sh[t] += u;
        __syncthreads();
    }
    if (t < SCAN_NB) partials[t] = sh[t] - v;
}

__global__ __launch_bounds__(256) void k_scan3(const int* __restrict__ excl,
                                               const int* __restrict__ partials,
                                               int* __restrict__ rowptr,
                                               int* __restrict__ cursor) {
    const int i = blockIdx.x * 256 + threadIdx.x;
    if (i < N_NODES) {
        int r = excl[i] + partials[blockIdx.x];
        rowptr[i] = r;
        cursor[i] = r;
    }
    if (i == 0) rowptr[N_NODES] = N_EDGES;
}

// ---------------------------------------------------------------------------
// fill CSR buckets
// ---------------------------------------------------------------------------
__global__ __launch_bounds__(256) void k_fill(const int* __restrict__ ei,
                                              const float* __restrict__ inv_sqrt,
                                              int* __restrict__ cursor,
                                              int* __restrict__ esrc,
                                              float* __restrict__ ecoef) {
    int e = blockIdx.x * 256 + threadIdx.x;
    if (e >= N_EDGES) return;
    int s = ei[e];
    int d = ei[N_EDGES + e];
    int pos = atomicAdd(&cursor[d], 1);
    esrc[pos] = s;
    ecoef[pos] = inv_sqrt[s] * inv_sqrt[d];
}

// ---------------------------------------------------------------------------
// GEMM: H(bf16) = act(A) @ W  (act = BN+ReLU when BN, identity otherwise)
// A fp32 [N_NODES,128]; W fp32 [128,NCOL]; H bf16.
// ---------------------------------------------------------------------------
template <int NCOL, bool BN>
__global__ __launch_bounds__(256) void k_gemm(
    const float* __restrict__ A, const float* __restrict__ W,
    const float* __restrict__ stats,
    const float* __restrict__ gamma, const float* __restrict__ beta,
    unsigned short* __restrict__ H) {
    constexpr int COLG = NCOL / 8;
    constexpr int RPT  = NCOL / 32;
    const int t = threadIdx.x;
    const int row0 = blockIdx.x * 64;

    __shared__ float As[64][132];
    __shared__ float sc_s[128], sh_s[128];

    if (BN) {
        if (t < 128) {
            float s  = stats[t];
            float sq = stats[128 + t];
            float mean = s * (1.0f / N_NODES);
            float var  = sq * (1.0f / N_NODES) - mean * mean;
            float sc = gamma[t] * rsqrtf(var + EPS);
            sc_s[t] = sc;
            sh_s[t] = beta[t] - mean * sc;
        }
        __syncthreads();
    }

    const int c4 = t & 31;
    const int rr = t >> 5;
#pragma unroll
    for (int i = 0; i < 8; i++) {
        int row = i * 8 + rr;
        float4 v = make_float4(0.f, 0.f, 0.f, 0.f);
        if (row0 + row < N_NODES)
            v = *(const float4*)&A[(size_t)(row0 + row) * 128 + c4 * 4];
        if (BN) {
            int c = c4 * 4;
            v.x = fmaxf(fmaf(v.x, sc_s[c + 0], sh_s[c + 0]), 0.f);
            v.y = fmaxf(fmaf(v.y, sc_s[c + 1], sh_s[c + 1]), 0.f);
            v.z = fmaxf(fmaf(v.z, sc_s[c + 2], sh_s[c + 2]), 0.f);
            v.w = fmaxf(fmaf(v.w, sc_s[c + 3], sh_s[c + 3]), 0.f);
        }
        *(float4*)&As[row][c4 * 4] = v;
    }
    __syncthreads();

    const int tx = t % COLG;
    const int ty = t / COLG;
    float acc[RPT][8];
#pragma unroll
    for (int r = 0; r < RPT; r++)
#pragma unroll
        for (int c = 0; c < 8; c++) acc[r][c] = 0.f;

    const float* Wp = W + tx * 8;
#pragma unroll 4
    for (int k = 0; k < 128; k++) {
        float a[RPT];
#pragma unroll
        for (int r = 0; r < RPT; r++) a[r] = As[ty * RPT + r][k];
        float4 w0 = *(const float4*)&Wp[k * NCOL];
        float4 w1 = *(const float4*)&Wp[k * NCOL + 4];
        float wv[8] = {w0.x, w0.y, w0.z, w0.w, w1.x, w1.y, w1.z, w1.w};
#pragma unroll
        for (int r = 0; r < RPT; r++)
#pragma unroll
            for (int c = 0; c < 8; c++)
                acc[r][c] = fmaf(a[r], wv[c], acc[r][c]);
    }

    // ---- epilogue: write H as bf16 (8 elems = 16 B per thread-row) ----
#pragma unroll
    for (int r = 0; r < RPT; r++) {
        int row = row0 + ty * RPT + r;
        if (row < N_NODES) {
            uint4 pk;
            pk.x = (unsigned)f2bf(acc[r][0]) | ((unsigned)f2bf(acc[r][1]) << 16);
            pk.y = (unsigned)f2bf(acc[r][2]) | ((unsigned)f2bf(acc[r][3]) << 16);
            pk.z = (unsigned)f2bf(acc[r][4]) | ((unsigned)f2bf(acc[r][5]) << 16);
            pk.w = (unsigned)f2bf(acc[r][6]) | ((unsigned)f2bf(acc[r][7]) << 16);
            *(uint4*)&H[(size_t)row * NCOL + tx * 8] = pk;
        }
    }
}

// ---------------------------------------------------------------------------
// CSR gather-aggregate from bf16 H, fp32 accumulate:
// OUT[n] = sum_e H[esrc[e]]*ecoef[e] + H[n]*inv_deg[n] + bias
// F/4 lanes per node; each lane: one uint2 (4 bf16) per edge.
// ---------------------------------------------------------------------------
template <int F>
__global__ __launch_bounds__(256) void k_agg(const int* __restrict__ rowptr,
                                             const int* __restrict__ esrc,
                                             const float* __restrict__ ecoef,
                                             const unsigned short* __restrict__ H,
                                             const float* __restrict__ inv_deg,
                                             const float* __restrict__ bias,
                                             float* __restrict__ OUT) {
    constexpr int LPN = F / 4;              // lanes per node (32 or 16)
    constexpr int NPB = 256 / LPN;          // nodes per block
    const int t = threadIdx.x;
    const int node = blockIdx.x * NPB + t / LPN;
    const int lane = t % LPN;
    if (node >= N_NODES) return;

    const uint2* __restrict__ Hv = (const uint2*)H;   // 4 bf16 per uint2
    const int beg = rowptr[node];
    const int end = rowptr[node + 1];

    float4 acc = make_float4(0.f, 0.f, 0.f, 0.f);
    int j = beg;
    for (; j + 1 < end; j += 2) {
        int s0 = esrc[j], s1 = esrc[j + 1];
        float c0 = ecoef[j], c1 = ecoef[j + 1];
        uint2 p0 = Hv[(size_t)s0 * LPN + lane];
        uint2 p1 = Hv[(size_t)s1 * LPN + lane];
        acc.x = fmaf(blo(p0.x), c0, acc.x); acc.y = fmaf(bhi(p0.x), c0, acc.y);
        acc.z = fmaf(blo(p0.y), c0, acc.z); acc.w = fmaf(bhi(p0.y), c0, acc.w);
        acc.x = fmaf(blo(p1.x), c1, acc.x); acc.y = fmaf(bhi(p1.x), c1, acc.y);
        acc.z = fmaf(blo(p1.y), c1, acc.z); acc.w = fmaf(bhi(p1.y), c1, acc.w);
    }
    if (j < end) {
        int s0 = esrc[j];
        float c0 = ecoef[j];
        uint2 p0 = Hv[(size_t)s0 * LPN + lane];
        acc.x = fmaf(blo(p0.x), c0, acc.x); acc.y = fmaf(bhi(p0.x), c0, acc.y);
        acc.z = fmaf(blo(p0.y), c0, acc.z); acc.w = fmaf(bhi(p0.y), c0, acc.w);
    }

    // self-loop + bias
    uint2 ps = Hv[(size_t)node * LPN + lane];
    float idv = inv_deg[node];
    float4 b4 = ((const float4*)bias)[lane];
    acc.x = fmaf(blo(ps.x), idv, acc.x) + b4.x;
    acc.y = fmaf(bhi(ps.x), idv, acc.y) + b4.y;
    acc.z = fmaf(blo(ps.y), idv, acc.z) + b4.z;
    acc.w = fmaf(bhi(ps.y), idv, acc.w) + b4.w;

    ((float4*)OUT)[(size_t)node * LPN + lane] = acc;
}

// ---------------------------------------------------------------------------
// column stats over fp32 A[N,128]
// ---------------------------------------------------------------------------
__global__ __launch_bounds__(256) void k_stats(const float* __restrict__ A,
                                               float* __restrict__ stats) {
    const int t  = threadIdx.x;
    const int c4 = t & 31;
    const int rr = t >> 5;
    float4 sum = make_float4(0.f, 0.f, 0.f, 0.f);
    float4 sq  = make_float4(0.f, 0.f, 0.f, 0.f);
    for (int row = blockIdx.x * 8 + rr; row < N_NODES; row += gridDim.x * 8) {
        float4 v = *(const float4*)&A[(size_t)row * 128 + c4 * 4];
        sum.x += v.x; sum.y += v.y; sum.z += v.z; sum.w += v.w;
        sq.x += v.x * v.x; sq.y += v.y * v.y; sq.z += v.z * v.z; sq.w += v.w * v.w;
    }
    __shared__ float4 red[2][8][32];
    red[0][rr][c4] = sum;
    red[1][rr][c4] = sq;
    __syncthreads();
    if (t < 32) {
        float4 s = make_float4(0.f, 0.f, 0.f, 0.f);
        float4 q = make_float4(0.f, 0.f, 0.f, 0.f);
#pragma unroll
        for (int i = 0; i < 8; i++) {
            float4 a = red[0][i][t];
            float4 b = red[1][i][t];
            s.x += a.x; s.y += a.y; s.z += a.z; s.w += a.w;
            q.x += b.x; q.y += b.y; q.z += b.z; q.w += b.w;
        }
        int c = t * 4;
        atomicAdd(&stats[c + 0], s.x); atomicAdd(&stats[c + 1], s.y);
        atomicAdd(&stats[c + 2], s.z); atomicAdd(&stats[c + 3], s.w);
        atomicAdd(&stats[128 + c + 0], q.x); atomicAdd(&stats[128 + c + 1], q.y);
        atomicAdd(&stats[128 + c + 2], q.z); atomicAdd(&stats[128 + c + 3], q.w);
    }
}

// ---------------------------------------------------------------------------
extern "C" void kernel_launch(void* const* d_in, const int* in_sizes, int n_in,
                              void* d_out, int out_size, void* d_ws, size_t ws_size,
                              hipStream_t stream) {
    const float* x   = (const float*)d_in[0];
    const int*   ei  = (const int*)d_in[1];
    const float* W1  = (const float*)d_in[2];
    const float* b1  = (const float*)d_in[3];
    const float* g1  = (const float*)d_in[4];
    const float* bt1 = (const float*)d_in[5];
    const float* W2  = (const float*)d_in[6];
    const float* b2  = (const float*)d_in[7];
    const float* g2  = (const float*)d_in[8];
    const float* bt2 = (const float*)d_in[9];
    const float* W3  = (const float*)d_in[10];
    const float* b3  = (const float*)d_in[11];
    float* out = (float*)d_out;                 // [N, 64]

    char* ws = (char*)d_ws;
    size_t off = 0;
    auto alloc = [&](size_t bytes) { char* p = ws + off; off += (bytes + 255) & ~(size_t)255; return p; };
    int*   deg      = (int*)  alloc((size_t)N_NODES * 4);
    float* inv_sqrt = (float*)alloc((size_t)N_NODES * 4);
    float* inv_deg  = (float*)alloc((size_t)N_NODES * 4);
    int*   excl     = (int*)  alloc((size_t)N_NODES * 4);
    int*   partials = (int*)  alloc(256 * 4);
    int*   rowptr   = (int*)  alloc((size_t)(N_NODES + 1) * 4);
    int*   cursor   = (int*)  alloc((size_t)N_NODES * 4);
    int*   esrc     = (int*)  alloc((size_t)N_EDGES * 4);
    float* ecoef    = (float*)alloc((size_t)N_EDGES * 4);
    float* stats1   = (float*)alloc(256 * 4);
    float* stats2   = (float*)alloc(256 * 4);
    unsigned short* h1 = (unsigned short*)alloc((size_t)N_NODES * 128 * 2);
    unsigned short* h2 = (unsigned short*)alloc((size_t)N_NODES * 128 * 2);
    unsigned short* h3 = (unsigned short*)alloc((size_t)N_NODES * 64 * 2);
    float* agg1     = (float*)alloc((size_t)N_NODES * 128 * 4);
    float* agg2     = (float*)alloc((size_t)N_NODES * 128 * 4);

    hipMemsetAsync(deg, 0, (size_t)N_NODES * 4, stream);
    hipMemsetAsync(stats1, 0, 256 * 4, stream);
    hipMemsetAsync(stats2, 0, 256 * 4, stream);

    k_prep<<<(N_EDGES + 255) / 256, 256, 0, stream>>>(ei, deg);
    k_inv<<<(N_NODES + 255) / 256, 256, 0, stream>>>(deg, inv_sqrt, inv_deg);
    k_scan1<<<SCAN_NB, 256, 0, stream>>>(deg, excl, partials);
    k_scan2<<<1, 256, 0, stream>>>(partials);
    k_scan3<<<SCAN_NB, 256, 0, stream>>>(excl, partials, rowptr, cursor);
    k_fill<<<(N_EDGES + 255) / 256, 256, 0, stream>>>(ei, inv_sqrt, cursor, esrc, ecoef);

    const int gemm_grid = (N_NODES + 63) / 64;

    // layer 1
    k_gemm<128, false><<<gemm_grid, 256, 0, stream>>>(x, W1, nullptr, nullptr, nullptr, h1);
    k_agg<128><<<(N_NODES + 7) / 8, 256, 0, stream>>>(rowptr, esrc, ecoef, h1, inv_deg, b1, agg1);
    k_stats<<<256, 256, 0, stream>>>(agg1, stats1);

    // layer 2
    k_gemm<128, true><<<gemm_grid, 256, 0, stream>>>(agg1, W2, stats1, g1, bt1, h2);
    k_agg<128><<<(N_NODES + 7) / 8, 256, 0, stream>>>(rowptr, esrc, ecoef, h2, inv_deg, b2, agg2);
    k_stats<<<256, 256, 0, stream>>>(agg2, stats2);

    // layer 3 (aggregate straight into d_out)
    k_gemm<64, true><<<gemm_grid, 256, 0, stream>>>(agg2, W3, stats2, g2, bt2, h3);
    k_agg<64><<<(N_NODES + 15) / 16, 256, 0, stream>>>(rowptr, esrc, ecoef, h3, inv_deg, b3, out);
}

// Round 5
// 379.197 us; speedup vs baseline: 9.7048x; 1.2370x over previous
//
#include <hip/hip_runtime.h>

#define N_NODES 50000
#define N_EDGES 800000
static constexpr float EPS = 1e-5f;
static constexpr int SCAN_NB = (N_NODES + 255) / 256;   // 196

using bf16x8 = __attribute__((ext_vector_type(8))) short;  // 8 bf16 (4 VGPRs)
using f32x4  = __attribute__((ext_vector_type(4))) float;

// ---- bf16 helpers (raw-bit, RNE) ----
static __device__ __forceinline__ unsigned short f2bf(float f) {
    unsigned int u = __float_as_uint(f);
    return (unsigned short)((u + 0x7FFFu + ((u >> 16) & 1u)) >> 16);
}
static __device__ __forceinline__ float blo(unsigned int w) { return __uint_as_float(w << 16); }
static __device__ __forceinline__ float bhi(unsigned int w) { return __uint_as_float(w & 0xffff0000u); }

// ---------------------------------------------------------------------------
// prep: in-degree histogram
// ---------------------------------------------------------------------------
__global__ __launch_bounds__(256) void k_prep(const int* __restrict__ ei,
                                              int* __restrict__ deg) {
    int e = blockIdx.x * 256 + threadIdx.x;
    if (e >= N_EDGES) return;
    atomicAdd(&deg[ei[N_EDGES + e]], 1);
}

__global__ __launch_bounds__(256) void k_inv(const int* __restrict__ deg,
                                             float* __restrict__ inv_sqrt,
                                             float* __restrict__ inv_deg) {
    int i = blockIdx.x * 256 + threadIdx.x;
    if (i >= N_NODES) return;
    float dg = (float)deg[i] + 1.0f;
    float r = rsqrtf(dg);
    inv_sqrt[i] = r;
    inv_deg[i] = r * r;
}

// ---------------------------------------------------------------------------
// hierarchical exclusive scan: deg[N] -> rowptr[N+1] (+cursor copy)
// ---------------------------------------------------------------------------
__global__ __launch_bounds__(256) void k_scan1(const int* __restrict__ deg,
                                               int* __restrict__ excl,
                                               int* __restrict__ partials) {
    const int t = threadIdx.x;
    const int i = blockIdx.x * 256 + t;
    int v = (i < N_NODES) ? deg[i] : 0;
    __shared__ int sh[256];
    sh[t] = v;
    __syncthreads();
    for (int off = 1; off < 256; off <<= 1) {
        int u = (t >= off) ? sh[t - off] : 0;
        __syncthreads();
        sh[t] += u;
        __syncthreads();
    }
    if (i < N_NODES) excl[i] = sh[t] - v;
    if (t == 255) partials[blockIdx.x] = sh[t];
}

__global__ __launch_bounds__(256) void k_scan2(int* __restrict__ partials) {
    const int t = threadIdx.x;
    int v = (t < SCAN_NB) ? partials[t] : 0;
    __shared__ int sh[256];
    sh[t] = v;
    __syncthreads();
    for (int off = 1; off < 256; off <<= 1) {
        int u = (t >= off) ? sh[t - off] : 0;
        __syncthreads();
        sh[t] += u;
        __syncthreads();
    }
    if (t < SCAN_NB) partials[t] = sh[t] - v;
}

__global__ __launch_bounds__(256) void k_scan3(const int* __restrict__ excl,
                                               const int* __restrict__ partials,
                                               int* __restrict__ rowptr,
                                               int* __restrict__ cursor) {
    const int i = blockIdx.x * 256 + threadIdx.x;
    if (i < N_NODES) {
        int r = excl[i] + partials[blockIdx.x];
        rowptr[i] = r;
        cursor[i] = r;
    }
    if (i == 0) rowptr[N_NODES] = N_EDGES;
}

// ---------------------------------------------------------------------------
// fill CSR buckets
// ---------------------------------------------------------------------------
__global__ __launch_bounds__(256) void k_fill(const int* __restrict__ ei,
                                              const float* __restrict__ inv_sqrt,
                                              int* __restrict__ cursor,
                                              int* __restrict__ esrc,
                                              float* __restrict__ ecoef) {
    int e = blockIdx.x * 256 + threadIdx.x;
    if (e >= N_EDGES) return;
    int s = ei[e];
    int d = ei[N_EDGES + e];
    int pos = atomicAdd(&cursor[d], 1);
    esrc[pos] = s;
    ecoef[pos] = inv_sqrt[s] * inv_sqrt[d];
}

// ---------------------------------------------------------------------------
// W fp32 [128][NCOL] -> bf16 packed in B-fragment order:
// Wf[((tn*4+s)*64 + lane)*8 + j] = W[k][n], n=tn*16+(lane&15), k=s*32+(lane>>4)*8+j
// ---------------------------------------------------------------------------
template <int NCOL>
__global__ __launch_bounds__(256) void k_wconv(const float* __restrict__ W,
                                               unsigned short* __restrict__ Wf) {
    int idx = blockIdx.x * 256 + threadIdx.x;
    if (idx >= NCOL * 128) return;
    int j  = idx & 7;
    int l  = (idx >> 3) & 63;
    int s  = (idx >> 9) & 3;
    int tn = idx >> 11;
    int n = tn * 16 + (l & 15);
    int k = s * 32 + (l >> 4) * 8 + j;
    Wf[idx] = f2bf(W[k * NCOL + n]);
}

// ---------------------------------------------------------------------------
// MFMA GEMM: H(bf16) = act(A) @ W, act = BN+ReLU if BN.
// A: fp32 (ABF16=false) or bf16 (true), [N,128]. Wf: fragment-packed bf16.
// 256 thr = 4 waves; block = 64 rows; wave = 16 rows x NCOL cols.
// ---------------------------------------------------------------------------
template <int NCOL, bool BN, bool ABF16>
__global__ __launch_bounds__(256) void k_gemm(
    const void* __restrict__ Ap, const unsigned short* __restrict__ Wf,
    const float* __restrict__ stats,
    const float* __restrict__ gamma, const float* __restrict__ beta,
    unsigned short* __restrict__ H) {
    const int t = threadIdx.x;
    const int row0 = blockIdx.x * 64;

    __shared__ unsigned short As[64 * 136];   // bf16, row stride 136 (+8 pad)
    __shared__ float sc_s[128], sh_s[128];

    if (BN) {
        if (t < 128) {
            float s  = stats[t];
            float sq = stats[128 + t];
            float mean = s * (1.0f / N_NODES);
            float var  = sq * (1.0f / N_NODES) - mean * mean;
            float sc = gamma[t] * rsqrtf(var + EPS);
            sc_s[t] = sc;
            sh_s[t] = beta[t] - mean * sc;
        }
        __syncthreads();
    }

    // ---- stage 64x128 A-tile into LDS as bf16 (BN+ReLU fused, fp32 math) ----
#pragma unroll
    for (int i = 0; i < 4; i++) {
        int q = i * 256 + t;          // 1024 units of 8 elements
        int row = q >> 4;
        int c8  = (q & 15) * 8;
        int grow = row0 + row;
        float v[8];
        if (grow < N_NODES) {
            if (ABF16) {
                uint4 p = *(const uint4*)((const unsigned short*)Ap + (size_t)grow * 128 + c8);
                v[0] = blo(p.x); v[1] = bhi(p.x); v[2] = blo(p.y); v[3] = bhi(p.y);
                v[4] = blo(p.z); v[5] = bhi(p.z); v[6] = blo(p.w); v[7] = bhi(p.w);
            } else {
                const float* Af = (const float*)Ap + (size_t)grow * 128 + c8;
                float4 f0 = *(const float4*)Af;
                float4 f1 = *(const float4*)(Af + 4);
                v[0] = f0.x; v[1] = f0.y; v[2] = f0.z; v[3] = f0.w;
                v[4] = f1.x; v[5] = f1.y; v[6] = f1.z; v[7] = f1.w;
            }
        } else {
#pragma unroll
            for (int j = 0; j < 8; j++) v[j] = 0.f;
        }
        if (BN) {
#pragma unroll
            for (int j = 0; j < 8; j++)
                v[j] = fmaxf(fmaf(v[j], sc_s[c8 + j], sh_s[c8 + j]), 0.f);
        }
        uint4 pk;
        pk.x = (unsigned)f2bf(v[0]) | ((unsigned)f2bf(v[1]) << 16);
        pk.y = (unsigned)f2bf(v[2]) | ((unsigned)f2bf(v[3]) << 16);
        pk.z = (unsigned)f2bf(v[4]) | ((unsigned)f2bf(v[5]) << 16);
        pk.w = (unsigned)f2bf(v[6]) | ((unsigned)f2bf(v[7]) << 16);
        *(uint4*)&As[row * 136 + c8] = pk;
    }
    __syncthreads();

    // ---- fragments & MFMA ----
    const int wv = t >> 6;      // wave 0..3 -> rows wv*16..wv*16+15
    const int l  = t & 63;
    const int m  = l & 15;      // A row within tile / D col within n-tile
    const int kq = l >> 4;      // quad

    bf16x8 afrag[4];
    const unsigned short* arow = &As[(wv * 16 + m) * 136 + kq * 8];
#pragma unroll
    for (int s = 0; s < 4; s++)
        afrag[s] = *(const bf16x8*)(arow + s * 32);   // k0 = s*32 + kq*8

    constexpr int NT = NCOL / 16;
#pragma unroll
    for (int tn = 0; tn < NT; tn++) {
        f32x4 acc = {0.f, 0.f, 0.f, 0.f};
#pragma unroll
        for (int s = 0; s < 4; s++) {
            bf16x8 b = *(const bf16x8*)&Wf[(size_t)((tn * 4 + s) * 64 + l) * 8];
            acc = __builtin_amdgcn_mfma_f32_16x16x32_bf16(afrag[s], b, acc, 0, 0, 0);
        }
        // D: col = tn*16 + m, row = wv*16 + kq*4 + r
        int col = tn * 16 + m;
#pragma unroll
        for (int r = 0; r < 4; r++) {
            int row = row0 + wv * 16 + kq * 4 + r;
            if (row < N_NODES) H[(size_t)row * NCOL + col] = f2bf(acc[r]);
        }
    }
}

// ---------------------------------------------------------------------------
// CSR gather-aggregate from bf16 H, fp32 accumulate.
// OUT bf16 (OUTBF) or fp32.
// ---------------------------------------------------------------------------
template <int F, bool OUTBF>
__global__ __launch_bounds__(256) void k_agg(const int* __restrict__ rowptr,
                                             const int* __restrict__ esrc,
                                             const float* __restrict__ ecoef,
                                             const unsigned short* __restrict__ H,
                                             const float* __restrict__ inv_deg,
                                             const float* __restrict__ bias,
                                             void* __restrict__ OUT) {
    constexpr int LPN = F / 4;              // lanes per node (32 or 16)
    constexpr int NPB = 256 / LPN;
    const int t = threadIdx.x;
    const int node = blockIdx.x * NPB + t / LPN;
    const int lane = t % LPN;
    if (node >= N_NODES) return;

    const uint2* __restrict__ Hv = (const uint2*)H;   // 4 bf16 per uint2
    const int beg = rowptr[node];
    const int end = rowptr[node + 1];

    float4 acc = make_float4(0.f, 0.f, 0.f, 0.f);
    int j = beg;
    for (; j + 1 < end; j += 2) {
        int s0 = esrc[j], s1 = esrc[j + 1];
        float c0 = ecoef[j], c1 = ecoef[j + 1];
        uint2 p0 = Hv[(size_t)s0 * LPN + lane];
        uint2 p1 = Hv[(size_t)s1 * LPN + lane];
        acc.x = fmaf(blo(p0.x), c0, acc.x); acc.y = fmaf(bhi(p0.x), c0, acc.y);
        acc.z = fmaf(blo(p0.y), c0, acc.z); acc.w = fmaf(bhi(p0.y), c0, acc.w);
        acc.x = fmaf(blo(p1.x), c1, acc.x); acc.y = fmaf(bhi(p1.x), c1, acc.y);
        acc.z = fmaf(blo(p1.y), c1, acc.z); acc.w = fmaf(bhi(p1.y), c1, acc.w);
    }
    if (j < end) {
        int s0 = esrc[j];
        float c0 = ecoef[j];
        uint2 p0 = Hv[(size_t)s0 * LPN + lane];
        acc.x = fmaf(blo(p0.x), c0, acc.x); acc.y = fmaf(bhi(p0.x), c0, acc.y);
        acc.z = fmaf(blo(p0.y), c0, acc.z); acc.w = fmaf(bhi(p0.y), c0, acc.w);
    }

    // self-loop + bias
    uint2 ps = Hv[(size_t)node * LPN + lane];
    float idv = inv_deg[node];
    float4 b4 = ((const float4*)bias)[lane];
    acc.x = fmaf(blo(ps.x), idv, acc.x) + b4.x;
    acc.y = fmaf(bhi(ps.x), idv, acc.y) + b4.y;
    acc.z = fmaf(blo(ps.y), idv, acc.z) + b4.z;
    acc.w = fmaf(bhi(ps.y), idv, acc.w) + b4.w;

    if (OUTBF) {
        uint2 pk;
        pk.x = (unsigned)f2bf(acc.x) | ((unsigned)f2bf(acc.y) << 16);
        pk.y = (unsigned)f2bf(acc.z) | ((unsigned)f2bf(acc.w) << 16);
        ((uint2*)OUT)[(size_t)node * LPN + lane] = pk;
    } else {
        ((float4*)OUT)[(size_t)node * LPN + lane] = acc;
    }
}

// ---------------------------------------------------------------------------
// column stats over bf16 A[N,128]: stats[0:128]=sum, [128:256]=sumsq
// ---------------------------------------------------------------------------
__global__ __launch_bounds__(256) void k_stats(const unsigned short* __restrict__ A,
                                               float* __restrict__ stats) {
    const int t  = threadIdx.x;
    const int c4 = t & 31;
    const int rr = t >> 5;
    float4 sum = make_float4(0.f, 0.f, 0.f, 0.f);
    float4 sq  = make_float4(0.f, 0.f, 0.f, 0.f);
    for (int row = blockIdx.x * 8 + rr; row < N_NODES; row += gridDim.x * 8) {
        uint2 p = *(const uint2*)&A[(size_t)row * 128 + c4 * 4];
        float vx = blo(p.x), vy = bhi(p.x), vz = blo(p.y), vw = bhi(p.y);
        sum.x += vx; sum.y += vy; sum.z += vz; sum.w += vw;
        sq.x += vx * vx; sq.y += vy * vy; sq.z += vz * vz; sq.w += vw * vw;
    }
    __shared__ float4 red[2][8][32];
    red[0][rr][c4] = sum;
    red[1][rr][c4] = sq;
    __syncthreads();
    if (t < 32) {
        float4 s = make_float4(0.f, 0.f, 0.f, 0.f);
        float4 q = make_float4(0.f, 0.f, 0.f, 0.f);
#pragma unroll
        for (int i = 0; i < 8; i++) {
            float4 a = red[0][i][t];
            float4 b = red[1][i][t];
            s.x += a.x; s.y += a.y; s.z += a.z; s.w += a.w;
            q.x += b.x; q.y += b.y; q.z += b.z; q.w += b.w;
        }
        int c = t * 4;
        atomicAdd(&stats[c + 0], s.x); atomicAdd(&stats[c + 1], s.y);
        atomicAdd(&stats[c + 2], s.z); atomicAdd(&stats[c + 3], s.w);
        atomicAdd(&stats[128 + c + 0], q.x); atomicAdd(&stats[128 + c + 1], q.y);
        atomicAdd(&stats[128 + c + 2], q.z); atomicAdd(&stats[128 + c + 3], q.w);
    }
}

// ---------------------------------------------------------------------------
extern "C" void kernel_launch(void* const* d_in, const int* in_sizes, int n_in,
                              void* d_out, int out_size, void* d_ws, size_t ws_size,
                              hipStream_t stream) {
    const float* x   = (const float*)d_in[0];
    const int*   ei  = (const int*)d_in[1];
    const float* W1  = (const float*)d_in[2];
    const float* b1  = (const float*)d_in[3];
    const float* g1  = (const float*)d_in[4];
    const float* bt1 = (const float*)d_in[5];
    const float* W2  = (const float*)d_in[6];
    const float* b2  = (const float*)d_in[7];
    const float* g2  = (const float*)d_in[8];
    const float* bt2 = (const float*)d_in[9];
    const float* W3  = (const float*)d_in[10];
    const float* b3  = (const float*)d_in[11];
    float* out = (float*)d_out;                 // [N, 64] fp32

    char* ws = (char*)d_ws;
    size_t off = 0;
    auto alloc = [&](size_t bytes) { char* p = ws + off; off += (bytes + 255) & ~(size_t)255; return p; };
    int*   deg      = (int*)  alloc((size_t)N_NODES * 4);
    float* inv_sqrt = (float*)alloc((size_t)N_NODES * 4);
    float* inv_deg  = (float*)alloc((size_t)N_NODES * 4);
    int*   excl     = (int*)  alloc((size_t)N_NODES * 4);
    int*   partials = (int*)  alloc(256 * 4);
    int*   rowptr   = (int*)  alloc((size_t)(N_NODES + 1) * 4);
    int*   cursor   = (int*)  alloc((size_t)N_NODES * 4);
    int*   esrc     = (int*)  alloc((size_t)N_EDGES * 4);
    float* ecoef    = (float*)alloc((size_t)N_EDGES * 4);
    float* stats1   = (float*)alloc(256 * 4);
    float* stats2   = (float*)alloc(256 * 4);
    unsigned short* Wf1 = (unsigned short*)alloc((size_t)128 * 128 * 2);
    unsigned short* Wf2 = (unsigned short*)alloc((size_t)128 * 128 * 2);
    unsigned short* Wf3 = (unsigned short*)alloc((size_t)64 * 128 * 2);
    unsigned short* h1  = (unsigned short*)alloc((size_t)N_NODES * 128 * 2);
    unsigned short* h2  = (unsigned short*)alloc((size_t)N_NODES * 128 * 2);
    unsigned short* h3  = (unsigned short*)alloc((size_t)N_NODES * 64 * 2);
    unsigned short* agg1 = (unsigned short*)alloc((size_t)N_NODES * 128 * 2);
    unsigned short* agg2 = (unsigned short*)alloc((size_t)N_NODES * 128 * 2);

    hipMemsetAsync(deg, 0, (size_t)N_NODES * 4, stream);
    hipMemsetAsync(stats1, 0, 256 * 4, stream);
    hipMemsetAsync(stats2, 0, 256 * 4, stream);

    k_prep<<<(N_EDGES + 255) / 256, 256, 0, stream>>>(ei, deg);
    k_inv<<<(N_NODES + 255) / 256, 256, 0, stream>>>(deg, inv_sqrt, inv_deg);
    k_scan1<<<SCAN_NB, 256, 0, stream>>>(deg, excl, partials);
    k_scan2<<<1, 256, 0, stream>>>(partials);
    k_scan3<<<SCAN_NB, 256, 0, stream>>>(excl, partials, rowptr, cursor);
    k_fill<<<(N_EDGES + 255) / 256, 256, 0, stream>>>(ei, inv_sqrt, cursor, esrc, ecoef);

    k_wconv<128><<<64, 256, 0, stream>>>(W1, Wf1);
    k_wconv<128><<<64, 256, 0, stream>>>(W2, Wf2);
    k_wconv<64><<<32, 256, 0, stream>>>(W3, Wf3);

    const int gemm_grid = (N_NODES + 63) / 64;

    // layer 1
    k_gemm<128, false, false><<<gemm_grid, 256, 0, stream>>>(x, Wf1, nullptr, nullptr, nullptr, h1);
    k_agg<128, true><<<(N_NODES + 7) / 8, 256, 0, stream>>>(rowptr, esrc, ecoef, h1, inv_deg, b1, agg1);
    k_stats<<<256, 256, 0, stream>>>(agg1, stats1);

    // layer 2
    k_gemm<128, true, true><<<gemm_grid, 256, 0, stream>>>(agg1, Wf2, stats1, g1, bt1, h2);
    k_agg<128, true><<<(N_NODES + 7) / 8, 256, 0, stream>>>(rowptr, esrc, ecoef, h2, inv_deg, b2, agg2);
    k_stats<<<256, 256, 0, stream>>>(agg2, stats2);

    // layer 3 (aggregate straight into d_out, fp32)
    k_gemm<64, true, true><<<gemm_grid, 256, 0, stream>>>(agg2, Wf3, stats2, g2, bt2, h3);
    k_agg<64, false><<<(N_NODES + 15) / 16, 256, 0, stream>>>(rowptr, esrc, ecoef, h3, inv_deg, b3, out);
}